// Round 4
// baseline (248.161 us; speedup 1.0000x reference)
//
#include <hip/hip_runtime.h>
#include <cstdint>
#include <math.h>

#define B 8
#define L 2048
#define D 256
#define H 128

typedef __attribute__((ext_vector_type(8))) _Float16 half8;
typedef __attribute__((ext_vector_type(4))) _Float16 half4t;
typedef __attribute__((ext_vector_type(4))) float f32x4;
typedef unsigned short ushort;
typedef unsigned int uint;

// Layouts:
//  pq/pk (B*L*H fp16) packed MFMA-frag blocks: block=(grow/16)*4+h/32,
//     elem=((h>>3)&3)*128+(grow&15)*8+(h&7)   [proven R4-R6]
//  vt (B*L*D fp16): block=((b*L+key)/32)*16+d/16, elem=((key&31)>>3)*128+(d&15)*8+(key&7)
//  S  (fp16): S[b][qt16][kt16][q16*16+k16], microtile-max-shifted (values <= 0)
//  tmax1[b][q][kt64=32] = max_k(s+bias1) per 64-key tile (f32)
//  tmax2[b][k][qt16=128] = max_q(s+bias2) per 16-q tile (f32)
//  mmax[b][qt16][kt16] = raw microtile max (f32)

// ---------------------------------------------------------------------------
// prep: masks -> float bias (0 / -inf), W -> fp16 fragment blocks.
// ---------------------------------------------------------------------------
__global__ void prep_kernel(const void* __restrict__ raw0,
                            const void* __restrict__ raw1,
                            const float* __restrict__ Wq,
                            const float* __restrict__ Wk,
                            float* __restrict__ fb1,
                            float* __restrict__ fb2,
                            _Float16* __restrict__ Wf) {
    const int t = threadIdx.x;
    const int z = blockIdx.y;
    {
        const void* raw = z ? raw1 : raw0;
        float* outb = z ? fb2 : fb1;
        const uint* wd = (const uint*)raw;
        __shared__ int flag;
        if (t == 0) flag = 0;
        __syncthreads();
        if (wd[t] > 1u) flag = 1;   // byte-bool layout iff some word >1
        __syncthreads();
        const int base = blockIdx.x * 1024;
        if (flag) {
            const uint8_t* by = (const uint8_t*)raw;
#pragma unroll
            for (int j = 0; j < 4; ++j) {
                int i = base + t + 256 * j;
                outb[i] = by[i] ? -INFINITY : 0.f;
            }
        } else {
#pragma unroll
            for (int j = 0; j < 4; ++j) {
                int i = base + t + 256 * j;
                outb[i] = wd[i] ? -INFINITY : 0.f;
            }
        }
    }
    {
        const float* Wsrc = z ? Wk : Wq;
        const int chunk = blockIdx.x * 256 + t;   // 0..4095
        const int h = chunk >> 5;
        const int d0 = (chunk & 31) * 8;
        float4 v0 = *(const float4*)(Wsrc + (size_t)h * 256 + d0);
        float4 v1 = *(const float4*)(Wsrc + (size_t)h * 256 + d0 + 4);
        half8 hv;
        hv[0] = (_Float16)v0.x; hv[1] = (_Float16)v0.y;
        hv[2] = (_Float16)v0.z; hv[3] = (_Float16)v0.w;
        hv[4] = (_Float16)v1.x; hv[5] = (_Float16)v1.y;
        hv[6] = (_Float16)v1.z; hv[7] = (_Float16)v1.w;
        const int db = d0 >> 5, dq = (d0 >> 3) & 3;
        size_t off = (size_t)z * 32768 +
                     ((size_t)((h >> 4) * 8 + db)) * 512 + dq * 128 + (h & 15) * 8;
        *(half8*)(Wf + off) = hv;
    }
}

// ---------------------------------------------------------------------------
// MFMA projections (unchanged): pq/pk fp16 packed.
// ---------------------------------------------------------------------------
__launch_bounds__(256, 2)
__global__ void proj_mfma_kernel(const float* __restrict__ queries,
                                 const float* __restrict__ keys,
                                 const _Float16* __restrict__ Wf,
                                 const float* __restrict__ scaling,
                                 _Float16* __restrict__ pqo,
                                 _Float16* __restrict__ pko) {
    const int t = threadIdx.x;
    const int w = t >> 6;
    const int lane = t & 63;
    const int l15 = lane & 15;
    const int quad = lane >> 4;
    const int z = blockIdx.z;
    const int half = blockIdx.y;
    const int r0 = blockIdx.x * 64;
    const float* in = z ? keys : queries;
    _Float16* outp = z ? pko : pqo;

    __shared__ __attribute__((aligned(16))) _Float16 Wl[32 * 512];
    __shared__ __attribute__((aligned(16))) _Float16 Af[4][8 * 512];

    {
        const _Float16* wsrc = Wf + ((size_t)z * 64 + half * 32) * 512;
#pragma unroll
        for (int i = 0; i < 8; ++i) {
            const int f = w * 8 + i;
            __builtin_amdgcn_global_load_lds(
                (const __attribute__((address_space(1))) uint*)(wsrc + f * 512 + lane * 8),
                (__attribute__((address_space(3))) uint*)(Wl + f * 512 + lane * 8),
                16, 0, 0);
        }
    }
    {
#pragma unroll
        for (int j = 0; j < 16; ++j) {
            const int idx = t + 256 * j;
            const int row = idx >> 6;
            const int c4 = idx & 63;
            float4 v = *(const float4*)(in + ((size_t)(r0 + row)) * 256 + c4 * 4);
            half4t h4;
            h4[0] = (_Float16)v.x; h4[1] = (_Float16)v.y;
            h4[2] = (_Float16)v.z; h4[3] = (_Float16)v.w;
            const int rt = row >> 4, rl = row & 15;
            const int d0 = c4 * 4;
            const int db = d0 >> 5, dq = (d0 >> 3) & 3, e = d0 & 7;
            *(half4t*)(&Af[rt][db * 512 + dq * 128 + rl * 8 + e]) = h4;
        }
    }
    __syncthreads();

    half8 a[8];
#pragma unroll
    for (int db = 0; db < 8; ++db)
        a[db] = *(const half8*)(&Af[w][db * 512 + lane * 8]);

    f32x4 acc[4];
#pragma unroll
    for (int hti = 0; hti < 4; ++hti) acc[hti] = (f32x4){0.f, 0.f, 0.f, 0.f};
#pragma unroll
    for (int db = 0; db < 8; ++db)
#pragma unroll
        for (int hti = 0; hti < 4; ++hti) {
            half8 bfrag = *(const half8*)(Wl + (hti * 8 + db) * 512 + lane * 8);
            acc[hti] = __builtin_amdgcn_mfma_f32_16x16x32_f16(a[db], bfrag, acc[hti], 0, 0, 0);
        }

    _Float16* S = Af[w];
#pragma unroll
    for (int hti = 0; hti < 4; ++hti) {
        const int hl_ = hti * 16 + l15;
        const int hb = hl_ >> 5, hq = (hl_ >> 3) & 3, e = hl_ & 7;
        const float scl = z ? scaling[half * 64 + hl_] : 1.f;
#pragma unroll
        for (int r = 0; r < 4; ++r) {
            float v = fmaxf(acc[hti][r], 0.f) * scl;
            S[hb * 512 + hq * 128 + (quad * 4 + r) * 8 + e] = (_Float16)v;
        }
    }
    const size_t grow16 = (size_t)(r0 >> 4) + w;
    _Float16* gout = outp + (grow16 * 4 + half * 2) * 512;
#pragma unroll
    for (int hb = 0; hb < 2; ++hb) {
        half8 vv = *(const half8*)(S + hb * 512 + lane * 8);
        *(half8*)(gout + hb * 512 + lane * 8) = vv;
    }
}

// ---------------------------------------------------------------------------
// V -> fp16 packed fragment layout (unchanged).
// ---------------------------------------------------------------------------
__global__ void vtrans_kernel(const float* __restrict__ v1,
                              const float* __restrict__ v2,
                              _Float16* __restrict__ vt1,
                              _Float16* __restrict__ vt2) {
    const int t = threadIdx.x;
    const int zz = blockIdx.z;
    const int b = zz & 7;
    const int which = zz >> 3;
    const float* src = (which ? v2 : v1) + (size_t)b * L * D;
    _Float16* dst = which ? vt2 : vt1;
    const int k0 = blockIdx.x * 64;
    const int d0 = blockIdx.y * 64;
    __shared__ float lt[64][65];
#pragma unroll
    for (int p = 0; p < 4; ++p) {
        int kr = p * 16 + (t >> 4);
        float4 v = *(const float4*)(src + (size_t)(k0 + kr) * D + d0 + (t & 15) * 4);
        lt[(t & 15) * 4 + 0][kr] = v.x;
        lt[(t & 15) * 4 + 1][kr] = v.y;
        lt[(t & 15) * 4 + 2][kr] = v.z;
        lt[(t & 15) * 4 + 3][kr] = v.w;
    }
    __syncthreads();
    const int d = t & 63;
    const int kk = (t >> 6) & 1;
    const int qp = t >> 7;
    const size_t tile = ((size_t)b * L + k0) / 32 + kk;
    const int ct = (d0 + d) >> 4;
    _Float16* base = dst + (tile * 16 + ct) * 512 + (d & 15) * 8;
#pragma unroll
    for (int s = 0; s < 2; ++s) {
        const int qv = qp * 2 + s;
        const float* lr = &lt[d][kk * 32 + qv * 8];
        half8 hv;
#pragma unroll
        for (int e = 0; e < 8; ++e) hv[e] = (_Float16)lr[e];
        *(half8*)(base + qv * 128) = hv;
    }
}

// ---------------------------------------------------------------------------
// score (unchanged): S = pq·pk^T once; fp16 microtiles shifted by microtile
// max; tmax1/tmax2/mmax side outputs.
// ---------------------------------------------------------------------------
__launch_bounds__(256)
__global__ void score_kernel(const _Float16* __restrict__ pq,
                             const _Float16* __restrict__ pk,
                             const float* __restrict__ fb1,
                             const float* __restrict__ fb2,
                             _Float16* __restrict__ Sb,
                             float* __restrict__ tmax1,
                             float* __restrict__ tmax2,
                             float* __restrict__ mmax) {
    const int t = threadIdx.x;
    const int w = t >> 6;
    const int lane = t & 63;
    const int l15 = lane & 15;
    const int quad = lane >> 4;
    const int bb = blockIdx.z;
    const int k0 = blockIdx.x * 64;
    const int q0 = blockIdx.y * 64;
    const size_t bL = (size_t)bb * L;
    const int qt16 = (q0 >> 4) + w;

    half8 aq[4];
    {
        const _Float16* qb = pq + ((bL + q0 + w * 16) >> 4) * 2048 + lane * 8;
#pragma unroll
        for (int hb = 0; hb < 4; ++hb) aq[hb] = *(const half8*)(qb + hb * 512);
    }

    f32x4 s[4];
#pragma unroll
    for (int jt = 0; jt < 4; ++jt) {
        const _Float16* kb = pk + ((bL + k0 + jt * 16) >> 4) * 2048 + lane * 8;
        f32x4 sv = (f32x4){0.f, 0.f, 0.f, 0.f};
#pragma unroll
        for (int hb = 0; hb < 4; ++hb) {
            half8 bk = *(const half8*)(kb + hb * 512);
            sv = __builtin_amdgcn_mfma_f32_16x16x32_f16(aq[hb], bk, sv, 0, 0, 0);
        }
        s[jt] = sv;
    }

    float b1j[4];
#pragma unroll
    for (int jt = 0; jt < 4; ++jt) b1j[jt] = fb1[bL + k0 + jt * 16 + l15];
    float4 b2v = *(const float4*)(fb2 + bL + q0 + w * 16 + quad * 4);
    float b2r[4] = {b2v.x, b2v.y, b2v.z, b2v.w};

    // tmax1: per q-row max over the 64 keys (biased by fb1)
#pragma unroll
    for (int r = 0; r < 4; ++r) {
        float m1 = -INFINITY;
#pragma unroll
        for (int jt = 0; jt < 4; ++jt) m1 = fmaxf(m1, s[jt][r] + b1j[jt]);
        m1 = fmaxf(m1, __shfl_xor(m1, 1));
        m1 = fmaxf(m1, __shfl_xor(m1, 2));
        m1 = fmaxf(m1, __shfl_xor(m1, 4));
        m1 = fmaxf(m1, __shfl_xor(m1, 8));
        if (l15 == 0)
            tmax1[(bL + q0 + w * 16 + quad * 4 + r) * 32 + blockIdx.x] = m1;
    }

    // per 16x16 microtile: tmax2 (biased by fb2) + raw mmax + shifted store
#pragma unroll
    for (int jt = 0; jt < 4; ++jt) {
        float m2 = -INFINITY, mm = -INFINITY;
#pragma unroll
        for (int r = 0; r < 4; ++r) {
            m2 = fmaxf(m2, s[jt][r] + b2r[r]);
            mm = fmaxf(mm, s[jt][r]);
        }
        m2 = fmaxf(m2, __shfl_xor(m2, 16));
        m2 = fmaxf(m2, __shfl_xor(m2, 32));
        if (quad == 0)
            tmax2[(bL + k0 + jt * 16 + l15) * 128 + qt16] = m2;
        mm = fmaxf(mm, __shfl_xor(mm, 1));
        mm = fmaxf(mm, __shfl_xor(mm, 2));
        mm = fmaxf(mm, __shfl_xor(mm, 4));
        mm = fmaxf(mm, __shfl_xor(mm, 8));
        mm = fmaxf(mm, __shfl_xor(mm, 16));
        mm = fmaxf(mm, __shfl_xor(mm, 32));
        const size_t mti = ((size_t)bb * 128 + qt16) * 128 + (k0 >> 4) + jt;
        if (lane == 0) mmax[mti] = mm;
        _Float16* sp = Sb + mti * 256 + l15;
#pragma unroll
        for (int r = 0; r < 4; ++r)
            sp[(quad * 4 + r) * 16] = (_Float16)(s[jt][r] - mm);
    }
}

// ---------------------------------------------------------------------------
// attn_pv v4: 512-thread blocks, 8 waves, d-split wave pairs. Wave w handles
// row-group (w&3, 16 rows) and d-half (w>>2, 128 cols). Same grid (512
// blocks) + same 80 KB LDS -> 2 blocks/CU but now 16 waves/CU = 4/SIMD
// (2x latency hiding). exp/softmax duplicated per wave pair (cheap VALU) in
// exchange for halved per-wave critical path. Per wave per stage: 4 V loads
// + 1 S load = 5 VMEM -> vmcnt(5)/0.
// ---------------------------------------------------------------------------
__launch_bounds__(512, 4)
__global__ void attn_pv_kernel(const _Float16* __restrict__ Sb,
                               const float* __restrict__ fb1,
                               const float* __restrict__ fb2,
                               const float* __restrict__ tmax1,
                               const float* __restrict__ tmax2,
                               const float* __restrict__ mmax,
                               const _Float16* __restrict__ vt1,
                               const _Float16* __restrict__ vt2,
                               float* __restrict__ out) {
    const int t = threadIdx.x;
    const int w = t >> 6;          // 0..7
    const int wq = w & 3;          // row-group (16 rows)
    const int wd = w >> 2;         // d-half (128 cols)
    const int lane = t & 63;
    const int l15 = lane & 15;
    const int quad = lane >> 4;
    const int bb = blockIdx.y;
    const int z = blockIdx.z;
    const int r0 = blockIdx.x * 64;
    const size_t bL = (size_t)bb * L;
    const int qtw = (r0 >> 4) + wq;    // this wave's 16-row tile index

    const _Float16* Vp = z ? vt2 : vt1;
    const float* fbb = (z ? fb2 : fb1) + bL;
    float* O = out + (z ? (size_t)B * L * D : 0);

    __shared__ __attribute__((aligned(16))) _Float16 kv[2][32 * 512];  // 64 KB
    __shared__ __attribute__((aligned(16))) _Float16 sst[2][4096];     // 16 KB

    // stage one 64-key tile: V = 32 KB (32 loads, 4/wave), S = 8 KB
    // (8 loads, 1/wave: wave w stages row-group w>>1, microtile-pair w&1).
    auto stage = [&](int it, int buf) {
        const _Float16* vb = Vp + ((bL + (size_t)it * 64) >> 5) * (size_t)(16 * 512);
#pragma unroll
        for (int i = 0; i < 4; ++i) {
            const int c = w * 4 + i;
            __builtin_amdgcn_global_load_lds(
                (const __attribute__((address_space(1))) uint*)(vb + c * 512 + lane * 8),
                (__attribute__((address_space(3))) uint*)(&kv[buf][c * 512] + lane * 8),
                16, 0, 0);
        }
        {
            const int rg = w >> 1, j = w & 1;
            const _Float16* ssrc;
            if (z == 0) {
                ssrc = Sb + (((size_t)bb * 128 + (r0 >> 4) + rg) * 128 + it * 4) * 256 +
                       j * 512 + lane * 8;
            } else {
                const int qt = it * 4 + j * 2 + (lane >> 5);
                ssrc = Sb + (((size_t)bb * 128 + qt) * 128 + (r0 >> 4) + rg) * 256 +
                       (lane & 31) * 8;
            }
            __builtin_amdgcn_global_load_lds(
                (const __attribute__((address_space(1))) uint*)ssrc,
                (__attribute__((address_space(3))) uint*)(&sst[buf][rg * 1024 + j * 512] + lane * 8),
                16, 0, 0);
        }
    };

    stage(0, 0);

    // row max per lane (row = r0 + wq*16 + l15), register-only reduction
    float mreg;
    {
        const int row = r0 + wq * 16 + l15;
        float mv = -INFINITY;
        if (z == 0) {
            const float4* p4 = (const float4*)(tmax1 + ((bL + row) << 5)) + quad * 2;
#pragma unroll
            for (int i = 0; i < 2; ++i) {
                float4 v = p4[i];
                mv = fmaxf(mv, fmaxf(fmaxf(v.x, v.y), fmaxf(v.z, v.w)));
            }
        } else {
            const float4* p4 = (const float4*)(tmax2 + ((bL + row) << 7)) + quad * 8;
#pragma unroll
            for (int i = 0; i < 8; ++i) {
                float4 v = p4[i];
                mv = fmaxf(mv, fmaxf(fmaxf(v.x, v.y), fmaxf(v.z, v.w)));
            }
        }
        mv = fmaxf(mv, __shfl_xor(mv, 16));
        mv = fmaxf(mv, __shfl_xor(mv, 32));
        mreg = fmaxf(mv, -1e30f);   // guard vs all-masked
    }

    stage(1, 1);

    // tile 0 landed for this wave (5 outstanding = tile 1); barrier makes it
    // landed for ALL waves.
    asm volatile("s_waitcnt vmcnt(5)" ::: "memory");
    __builtin_amdgcn_sched_barrier(0);
    __builtin_amdgcn_s_barrier();
    __builtin_amdgcn_sched_barrier(0);

    f32x4 acc[8];
#pragma unroll
    for (int ct = 0; ct < 8; ++ct) acc[ct] = (f32x4){0.f, 0.f, 0.f, 0.f};
    float lsum = 0.f;

    for (int it = 0; it < 32; ++it) {
        const int buf = it & 1;
#pragma unroll
        for (int jt2 = 0; jt2 < 2; ++jt2) {
            const int mt = jt2 * 2 + (quad >> 1);   // microtile within tile
            // microtile-max correction
            float c;
            if (z == 0)
                c = mmax[((size_t)bb * 128 + qtw) * 128 + it * 4 + mt] - mreg;
            else
                c = mmax[((size_t)bb * 128 + it * 4 + mt) * 128 + qtw] - mreg;
            // inner-axis mask bias (8 consecutive)
            float bj[8];
            {
                const float4* bp = (const float4*)(fbb + it * 64 + jt2 * 32 + quad * 8);
                float4 b0 = bp[0], b1 = bp[1];
                bj[0] = b0.x; bj[1] = b0.y; bj[2] = b0.z; bj[3] = b0.w;
                bj[4] = b1.x; bj[5] = b1.y; bj[6] = b1.z; bj[7] = b1.w;
            }
            // scores from staged LDS
            float pj[8];
            if (z == 0) {
                const _Float16* sl =
                    &sst[buf][wq * 1024 + mt * 256 + l15 * 16 + (quad & 1) * 8];
                half8 sv = *(const half8*)sl;
#pragma unroll
                for (int j = 0; j < 8; ++j) pj[j] = (float)sv[j];
            } else {
                const _Float16* sl = &sst[buf][wq * 1024 + mt * 256 + l15];
#pragma unroll
                for (int j = 0; j < 8; ++j)
                    pj[j] = (float)sl[((quad & 1) * 8 + j) * 16];
            }
            // P = exp(s' + c + bias), fp16-rounded for num/denom consistency
            half8 pa;
#pragma unroll
            for (int j = 0; j < 8; ++j) {
                float p = __expf(pj[j] + c + bj[j]);
                pa[j] = (_Float16)p;
                lsum += (float)pa[j];
            }
            // PV over this 32-key half, this wave's d-half
            const _Float16* kb = &kv[buf][jt2 * 16 * 512];
#pragma unroll
            for (int ct = 0; ct < 8; ++ct) {
                half8 bv = *(const half8*)(kb + (wd * 8 + ct) * 512 + lane * 8);
                acc[ct] = __builtin_amdgcn_mfma_f32_16x16x32_f16(pa, bv, acc[ct], 0, 0, 0);
            }
        }

        if (it < 31) {
            // release buf: all waves done reading it
            __builtin_amdgcn_s_barrier();
            __builtin_amdgcn_sched_barrier(0);
            if (it + 2 < 32) {
                stage(it + 2, buf);
                // tile it+1 landed (5 newest outstanding = tile it+2)
                asm volatile("s_waitcnt vmcnt(5)" ::: "memory");
            } else {
                asm volatile("s_waitcnt vmcnt(0)" ::: "memory");
            }
            __builtin_amdgcn_sched_barrier(0);
            // acquire tile it+1 across all waves
            __builtin_amdgcn_s_barrier();
            __builtin_amdgcn_sched_barrier(0);
        }
    }

    // combine l across quads (lanes with same l15 hold same row)
    lsum += __shfl_xor(lsum, 16);
    lsum += __shfl_xor(lsum, 32);
    float inv = (lsum > 0.f) ? (1.f / lsum) : 0.f;

#pragma unroll
    for (int r = 0; r < 4; ++r) {
        const float invr = __shfl(inv, quad * 4 + r);
        float* orow = O + (bL + r0 + wq * 16 + quad * 4 + r) * (size_t)D + wd * 128 + l15;
#pragma unroll
        for (int ct = 0; ct < 8; ++ct)
            orow[ct * 16] = acc[ct][r] * invr;
    }
}

extern "C" void kernel_launch(void* const* d_in, const int* in_sizes, int n_in,
                              void* d_out, int out_size, void* d_ws, size_t ws_size,
                              hipStream_t stream) {
    const float* queries  = (const float*)d_in[0];
    const float* keys     = (const float*)d_in[1];
    const float* values_1 = (const float*)d_in[2];
    const void*  v1_mask  = d_in[3];
    const float* values_2 = (const float*)d_in[4];
    const void*  v2_mask  = d_in[5];
    const float* Wq       = (const float*)d_in[6];
    const float* Wk       = (const float*)d_in[7];
    const float* scaling  = (const float*)d_in[8];
    float* out = (float*)d_out;

    _Float16* pqw = (_Float16*)d_ws;                       // B*L*H   (4 MB)
    _Float16* pkw = pqw + (size_t)B * L * H;               // 4 MB
    _Float16* vt1 = pkw + (size_t)B * L * H;               // B*L*D   (8 MB)
    _Float16* vt2 = vt1 + (size_t)B * L * D;               // 8 MB
    _Float16* Sb  = vt2 + (size_t)B * L * D;               // B*128*128*256 (64 MB)
    float* fb1   = (float*)(Sb + (size_t)B * 128 * 128 * 256);  // 64 KB
    float* fb2   = fb1 + B * L;                            // 64 KB
    float* tmax1 = fb2 + B * L;                            // B*L*32   (2 MB)
    float* tmax2 = tmax1 + (size_t)B * L * 32;             // B*L*128  (8 MB)
    float* mmaxp = tmax2 + (size_t)B * L * 128;            // B*128*128 (512 KB)
    _Float16* Wf = (_Float16*)(mmaxp + (size_t)B * 128 * 128);  // 128 KB

    prep_kernel<<<dim3(16, 2), 256, 0, stream>>>(
        v1_mask, v2_mask, Wq, Wk, fb1, fb2, Wf);
    proj_mfma_kernel<<<dim3(B * L / 64, 2, 2), 256, 0, stream>>>(
        queries, keys, Wf, scaling, pqw, pkw);
    vtrans_kernel<<<dim3(L / 64, D / 64, B * 2), 256, 0, stream>>>(
        values_1, values_2, vt1, vt2);
    score_kernel<<<dim3(L / 64, L / 64, B), 256, 0, stream>>>(
        pqw, pkw, fb1, fb2, Sb, tmax1, tmax2, mmaxp);
    attn_pv_kernel<<<dim3(L / 64, B, 2), 512, 0, stream>>>(
        Sb, fb1, fb2, tmax1, tmax2, mmaxp, vt1, vt2, out);
}

// Round 6
// 227.387 us; speedup vs baseline: 1.0914x; 1.0914x over previous
//
#include <hip/hip_runtime.h>
#include <cstdint>
#include <math.h>

#define B 8
#define L 2048
#define D 256
#define H 128

typedef __attribute__((ext_vector_type(8))) _Float16 half8;
typedef __attribute__((ext_vector_type(4))) _Float16 half4t;
typedef __attribute__((ext_vector_type(2))) _Float16 half2v;
typedef __attribute__((ext_vector_type(4))) float f32x4;
typedef unsigned short ushort;
typedef unsigned int uint;

// Layouts:
//  pq/pk (B*L*H fp16) packed MFMA-frag blocks: block=(grow/16)*4+h/32,
//     elem=((h>>3)&3)*128+(grow&15)*8+(h&7)   [proven R4-R6]
//  vt (B*L*D fp16): block=((b*L+key)/32)*16+d/16, elem=((key&31)>>3)*128+(d&15)*8+(key&7)
// Fused attention (R5/R6): no S/tmax/mmax materialization. Both branches run
// the same kernel with pq/pk swapped:
//   z=0: rows=q, inner=keys,  S^T = pk·pq^T, V=vt1, bias=fb1 (over keys)
//   z=1: rows=k, inner=query, S^T = pq·pk^T, V=vt2, bias=fb2 (over queries)

// ---------------------------------------------------------------------------
// prep: masks -> float bias (0 / -inf), W -> fp16 fragment blocks.
// ---------------------------------------------------------------------------
__global__ void prep_kernel(const void* __restrict__ raw0,
                            const void* __restrict__ raw1,
                            const float* __restrict__ Wq,
                            const float* __restrict__ Wk,
                            float* __restrict__ fb1,
                            float* __restrict__ fb2,
                            _Float16* __restrict__ Wf) {
    const int t = threadIdx.x;
    const int z = blockIdx.y;
    {
        const void* raw = z ? raw1 : raw0;
        float* outb = z ? fb2 : fb1;
        const uint* wd = (const uint*)raw;
        __shared__ int flag;
        if (t == 0) flag = 0;
        __syncthreads();
        if (wd[t] > 1u) flag = 1;   // byte-bool layout iff some word >1
        __syncthreads();
        const int base = blockIdx.x * 1024;
        if (flag) {
            const uint8_t* by = (const uint8_t*)raw;
#pragma unroll
            for (int j = 0; j < 4; ++j) {
                int i = base + t + 256 * j;
                outb[i] = by[i] ? -INFINITY : 0.f;
            }
        } else {
#pragma unroll
            for (int j = 0; j < 4; ++j) {
                int i = base + t + 256 * j;
                outb[i] = wd[i] ? -INFINITY : 0.f;
            }
        }
    }
    {
        const float* Wsrc = z ? Wk : Wq;
        const int chunk = blockIdx.x * 256 + t;   // 0..4095
        const int h = chunk >> 5;
        const int d0 = (chunk & 31) * 8;
        float4 v0 = *(const float4*)(Wsrc + (size_t)h * 256 + d0);
        float4 v1 = *(const float4*)(Wsrc + (size_t)h * 256 + d0 + 4);
        half8 hv;
        hv[0] = (_Float16)v0.x; hv[1] = (_Float16)v0.y;
        hv[2] = (_Float16)v0.z; hv[3] = (_Float16)v0.w;
        hv[4] = (_Float16)v1.x; hv[5] = (_Float16)v1.y;
        hv[6] = (_Float16)v1.z; hv[7] = (_Float16)v1.w;
        const int db = d0 >> 5, dq = (d0 >> 3) & 3;
        size_t off = (size_t)z * 32768 +
                     ((size_t)((h >> 4) * 8 + db)) * 512 + dq * 128 + (h & 15) * 8;
        *(half8*)(Wf + off) = hv;
    }
}

// ---------------------------------------------------------------------------
// MFMA projections (unchanged): pq/pk fp16 packed.
// ---------------------------------------------------------------------------
__launch_bounds__(256, 2)
__global__ void proj_mfma_kernel(const float* __restrict__ queries,
                                 const float* __restrict__ keys,
                                 const _Float16* __restrict__ Wf,
                                 const float* __restrict__ scaling,
                                 _Float16* __restrict__ pqo,
                                 _Float16* __restrict__ pko) {
    const int t = threadIdx.x;
    const int w = t >> 6;
    const int lane = t & 63;
    const int l15 = lane & 15;
    const int quad = lane >> 4;
    const int z = blockIdx.z;
    const int half = blockIdx.y;
    const int r0 = blockIdx.x * 64;
    const float* in = z ? keys : queries;
    _Float16* outp = z ? pko : pqo;

    __shared__ __attribute__((aligned(16))) _Float16 Wl[32 * 512];
    __shared__ __attribute__((aligned(16))) _Float16 Af[4][8 * 512];

    {
        const _Float16* wsrc = Wf + ((size_t)z * 64 + half * 32) * 512;
#pragma unroll
        for (int i = 0; i < 8; ++i) {
            const int f = w * 8 + i;
            __builtin_amdgcn_global_load_lds(
                (const __attribute__((address_space(1))) uint*)(wsrc + f * 512 + lane * 8),
                (__attribute__((address_space(3))) uint*)(Wl + f * 512 + lane * 8),
                16, 0, 0);
        }
    }
    {
#pragma unroll
        for (int j = 0; j < 16; ++j) {
            const int idx = t + 256 * j;
            const int row = idx >> 6;
            const int c4 = idx & 63;
            float4 v = *(const float4*)(in + ((size_t)(r0 + row)) * 256 + c4 * 4);
            half4t h4;
            h4[0] = (_Float16)v.x; h4[1] = (_Float16)v.y;
            h4[2] = (_Float16)v.z; h4[3] = (_Float16)v.w;
            const int rt = row >> 4, rl = row & 15;
            const int d0 = c4 * 4;
            const int db = d0 >> 5, dq = (d0 >> 3) & 3, e = d0 & 7;
            *(half4t*)(&Af[rt][db * 512 + dq * 128 + rl * 8 + e]) = h4;
        }
    }
    __syncthreads();

    half8 a[8];
#pragma unroll
    for (int db = 0; db < 8; ++db)
        a[db] = *(const half8*)(&Af[w][db * 512 + lane * 8]);

    f32x4 acc[4];
#pragma unroll
    for (int hti = 0; hti < 4; ++hti) acc[hti] = (f32x4){0.f, 0.f, 0.f, 0.f};
#pragma unroll
    for (int db = 0; db < 8; ++db)
#pragma unroll
        for (int hti = 0; hti < 4; ++hti) {
            half8 bfrag = *(const half8*)(Wl + (hti * 8 + db) * 512 + lane * 8);
            acc[hti] = __builtin_amdgcn_mfma_f32_16x16x32_f16(a[db], bfrag, acc[hti], 0, 0, 0);
        }

    _Float16* S = Af[w];
#pragma unroll
    for (int hti = 0; hti < 4; ++hti) {
        const int hl_ = hti * 16 + l15;
        const int hb = hl_ >> 5, hq = (hl_ >> 3) & 3, e = hl_ & 7;
        const float scl = z ? scaling[half * 64 + hl_] : 1.f;
#pragma unroll
        for (int r = 0; r < 4; ++r) {
            float v = fmaxf(acc[hti][r], 0.f) * scl;
            S[hb * 512 + hq * 128 + (quad * 4 + r) * 8 + e] = (_Float16)v;
        }
    }
    const size_t grow16 = (size_t)(r0 >> 4) + w;
    _Float16* gout = outp + (grow16 * 4 + half * 2) * 512;
#pragma unroll
    for (int hb = 0; hb < 2; ++hb) {
        half8 vv = *(const half8*)(S + hb * 512 + lane * 8);
        *(half8*)(gout + hb * 512 + lane * 8) = vv;
    }
}

// ---------------------------------------------------------------------------
// V -> fp16 packed fragment layout (unchanged).
// ---------------------------------------------------------------------------
__global__ void vtrans_kernel(const float* __restrict__ v1,
                              const float* __restrict__ v2,
                              _Float16* __restrict__ vt1,
                              _Float16* __restrict__ vt2) {
    const int t = threadIdx.x;
    const int zz = blockIdx.z;
    const int b = zz & 7;
    const int which = zz >> 3;
    const float* src = (which ? v2 : v1) + (size_t)b * L * D;
    _Float16* dst = which ? vt2 : vt1;
    const int k0 = blockIdx.x * 64;
    const int d0 = blockIdx.y * 64;
    __shared__ float lt[64][65];
#pragma unroll
    for (int p = 0; p < 4; ++p) {
        int kr = p * 16 + (t >> 4);
        float4 v = *(const float4*)(src + (size_t)(k0 + kr) * D + d0 + (t & 15) * 4);
        lt[(t & 15) * 4 + 0][kr] = v.x;
        lt[(t & 15) * 4 + 1][kr] = v.y;
        lt[(t & 15) * 4 + 2][kr] = v.z;
        lt[(t & 15) * 4 + 3][kr] = v.w;
    }
    __syncthreads();
    const int d = t & 63;
    const int kk = (t >> 6) & 1;
    const int qp = t >> 7;
    const size_t tile = ((size_t)b * L + k0) / 32 + kk;
    const int ct = (d0 + d) >> 4;
    _Float16* base = dst + (tile * 16 + ct) * 512 + (d & 15) * 8;
#pragma unroll
    for (int s = 0; s < 2; ++s) {
        const int qv = qp * 2 + s;
        const float* lr = &lt[d][kk * 32 + qv * 8];
        half8 hv;
#pragma unroll
        for (int e = 0; e < 8; ++e) hv[e] = (_Float16)lr[e];
        *(half8*)(base + qv * 128) = hv;
    }
}

// ---------------------------------------------------------------------------
// attn_fused: score + online softmax + PV in one pass (flash-style).
// Block = 64 out-rows (4 waves x 16), key-tiles of 32, double-buffered LDS
// (K-frags 8 KB + V-frags 16 KB per tile; 52 KB total incl. P-bounce).
// S^T = mfma(Kfrag, Qfrag) so lane holds P^T[key=quad*4+r][q=l15]; the PV
// B-fragment (P^T, k=quad*8+e) is built via a 1 KB per-wave LDS bounce
// (4 ds_write_b32 + 1 ds_read_b128, wave-local, no barrier).
// Online softmax with defer-max THR=8 (rescale almost never fires).
// Grid (L/64, B, 2), block 256.
// ---------------------------------------------------------------------------
__launch_bounds__(256, 2)
__global__ void attn_fused_kernel(const _Float16* __restrict__ pqw,
                                  const _Float16* __restrict__ pkw,
                                  const float* __restrict__ fb1,
                                  const float* __restrict__ fb2,
                                  const _Float16* __restrict__ vt1,
                                  const _Float16* __restrict__ vt2,
                                  float* __restrict__ out) {
    const int t = threadIdx.x;
    const int w = t >> 6;
    const int lane = t & 63;
    const int l15 = lane & 15;
    const int quad = lane >> 4;
    const int bb = blockIdx.y;
    const int z = blockIdx.z;
    const int r0 = blockIdx.x * 64;
    const size_t bL = (size_t)bb * L;

    const _Float16* Qp = z ? pkw : pqw;   // rows side
    const _Float16* Kp = z ? pqw : pkw;   // inner (reduction) side
    const _Float16* Vp = z ? vt2 : vt1;
    const float* fbb = (z ? fb2 : fb1) + bL;
    float* O = out + (z ? (size_t)B * L * D : 0);

    __shared__ __attribute__((aligned(16))) _Float16 klds[2][4096];   // 16 KB
    __shared__ __attribute__((aligned(16))) _Float16 vlds[2][8192];   // 32 KB
    __shared__ __attribute__((aligned(16))) _Float16 plds[4][512];    //  4 KB

    // stage one 32-key tile: K-frags (2 blocks of 2048 halfs, contiguous)
    // + V-frags (one 16x512 block). 24 loads/block = 6/wave.
    auto stage = [&](int it, int buf) {
        const _Float16* ksrc = Kp + ((bL + it * 32) >> 4) * 2048;
#pragma unroll
        for (int i = 0; i < 2; ++i) {
            const int c = w * 2 + i;
            __builtin_amdgcn_global_load_lds(
                (const __attribute__((address_space(1))) uint*)(ksrc + c * 512 + lane * 8),
                (__attribute__((address_space(3))) uint*)(&klds[buf][c * 512] + lane * 8),
                16, 0, 0);
        }
        const _Float16* vsrc = Vp + ((bL + it * 32) >> 5) * (size_t)8192;
#pragma unroll
        for (int i = 0; i < 4; ++i) {
            const int c = w * 4 + i;
            __builtin_amdgcn_global_load_lds(
                (const __attribute__((address_space(1))) uint*)(vsrc + c * 512 + lane * 8),
                (__attribute__((address_space(3))) uint*)(&vlds[buf][c * 512] + lane * 8),
                16, 0, 0);
        }
    };

    // Q fragments for this wave's 16 rows (rows r0+w*16 .. +15)
    half8 aq[4];
    {
        const _Float16* qb = Qp + ((bL + r0 + w * 16) >> 4) * 2048 + lane * 8;
#pragma unroll
        for (int hb = 0; hb < 4; ++hb) aq[hb] = *(const half8*)(qb + hb * 512);
    }

    stage(0, 0);
    // bias for tile 0 (key = quad*4+r of mt0 / mt1)
    float4 bc0 = *(const float4*)(fbb + quad * 4);
    float4 bc1 = *(const float4*)(fbb + 16 + quad * 4);
    stage(1, 1);

    asm volatile("s_waitcnt vmcnt(6)" ::: "memory");
    __builtin_amdgcn_sched_barrier(0);
    __builtin_amdgcn_s_barrier();
    __builtin_amdgcn_sched_barrier(0);

    f32x4 acc[16];
#pragma unroll
    for (int ct = 0; ct < 16; ++ct) acc[ct] = (f32x4){0.f, 0.f, 0.f, 0.f};
    float lsum = 0.f;
    float m = -1e30f;

    const int NT = 64;
#pragma unroll 2
    for (int it = 0; it < NT; ++it) {
        const int buf = it & 1;

        // prefetch next tile's bias into regs
        float4 bn0 = bc0, bn1 = bc1;
        if (it + 1 < NT) {
            bn0 = *(const float4*)(fbb + (it + 1) * 32 + quad * 4);
            bn1 = *(const float4*)(fbb + (it + 1) * 32 + 16 + quad * 4);
        }

        // S^T = K-tile x Q: s[mt][r] = S^T[key=mt*16+quad*4+r][q=l15]
        f32x4 s0 = (f32x4){0.f, 0.f, 0.f, 0.f};
        f32x4 s1 = (f32x4){0.f, 0.f, 0.f, 0.f};
#pragma unroll
        for (int hb = 0; hb < 4; ++hb) {
            half8 kf0 = *(const half8*)(&klds[buf][hb * 512 + lane * 8]);
            half8 kf1 = *(const half8*)(&klds[buf][2048 + hb * 512 + lane * 8]);
            s0 = __builtin_amdgcn_mfma_f32_16x16x32_f16(kf0, aq[hb], s0, 0, 0, 0);
            s1 = __builtin_amdgcn_mfma_f32_16x16x32_f16(kf1, aq[hb], s1, 0, 0, 0);
        }
        // bias + tile max (row = q = l15; reduce over quads)
        float sv0[4], sv1[4];
        float mt_ = -INFINITY;
#pragma unroll
        for (int r = 0; r < 4; ++r) {
            sv0[r] = s0[r] + ((const float*)&bc0)[r];
            sv1[r] = s1[r] + ((const float*)&bc1)[r];
            mt_ = fmaxf(mt_, fmaxf(sv0[r], sv1[r]));
        }
        mt_ = fmaxf(mt_, __shfl_xor(mt_, 16));
        mt_ = fmaxf(mt_, __shfl_xor(mt_, 32));

        // online max with defer threshold 8 (rescale rare)
        if (!__all(mt_ <= m + 8.f)) {
            float mn = fmaxf(m, mt_);
            float sc = __expf(m - mn);
            m = mn;
            lsum *= sc;
#pragma unroll
            for (int ct = 0; ct < 16; ++ct) acc[ct] *= sc;
        }

        // P = exp(s - m), partial row sum, pack fp16
        float psum = 0.f;
        float p0[4], p1[4];
#pragma unroll
        for (int r = 0; r < 4; ++r) {
            p0[r] = __expf(sv0[r] - m);
            p1[r] = __expf(sv1[r] - m);
            psum += p0[r] + p1[r];
        }
        lsum += psum;
        half2v q00; q00[0] = (_Float16)p0[0]; q00[1] = (_Float16)p0[1];
        half2v q01; q01[0] = (_Float16)p0[2]; q01[1] = (_Float16)p0[3];
        half2v q10; q10[0] = (_Float16)p1[0]; q10[1] = (_Float16)p1[1];
        half2v q11; q11[0] = (_Float16)p1[2]; q11[1] = (_Float16)p1[3];
        // bounce P^T into B-frag layout: elem(key,q) = (key>>3)*128 + q*8 + (key&7)
        _Float16* pw = &plds[w][0];
        const int eb0 = (quad >> 1) * 128 + l15 * 8 + (quad & 1) * 4;
        const int eb1 = (2 + (quad >> 1)) * 128 + l15 * 8 + (quad & 1) * 4;
        *(half2v*)(pw + eb0) = q00;
        *(half2v*)(pw + eb0 + 2) = q01;
        *(half2v*)(pw + eb1) = q10;
        *(half2v*)(pw + eb1 + 2) = q11;
        half8 pfrag = *(const half8*)(pw + lane * 8);   // wave-local RAW, lgkmcnt by compiler

        // PV: out^T[d][q] += V^T x P^T  (A = V-frag direct from vt layout)
#pragma unroll
        for (int ct = 0; ct < 16; ++ct) {
            half8 vf = *(const half8*)(&vlds[buf][ct * 512 + lane * 8]);
            acc[ct] = __builtin_amdgcn_mfma_f32_16x16x32_f16(vf, pfrag, acc[ct], 0, 0, 0);
        }

        bc0 = bn0; bc1 = bn1;

        if (it < NT - 1) {
            // release buf (all waves finished reading it)
            __builtin_amdgcn_s_barrier();
            __builtin_amdgcn_sched_barrier(0);
            if (it + 2 < NT) {
                stage(it + 2, buf);
                // tile it+1 landed (6 newest outstanding = tile it+2)
                asm volatile("s_waitcnt vmcnt(6)" ::: "memory");
            } else {
                asm volatile("s_waitcnt vmcnt(0)" ::: "memory");
            }
            __builtin_amdgcn_sched_barrier(0);
            __builtin_amdgcn_s_barrier();
            __builtin_amdgcn_sched_barrier(0);
        }
    }

    // finish softmax denom: reduce across quads (row = l15)
    lsum += __shfl_xor(lsum, 16);
    lsum += __shfl_xor(lsum, 32);
    const float inv = (lsum > 0.f) ? (1.f / lsum) : 0.f;

    // store: lane holds out[q=r0+w*16+l15][d=ct*16+quad*4+r] -> f32x4 stores
    const int qrow = r0 + w * 16 + l15;
    float* orow = O + (bL + qrow) * (size_t)D + quad * 4;
#pragma unroll
    for (int ct = 0; ct < 16; ++ct) {
        f32x4 v = acc[ct] * inv;
        *(f32x4*)(orow + ct * 16) = v;
    }
}

extern "C" void kernel_launch(void* const* d_in, const int* in_sizes, int n_in,
                              void* d_out, int out_size, void* d_ws, size_t ws_size,
                              hipStream_t stream) {
    const float* queries  = (const float*)d_in[0];
    const float* keys     = (const float*)d_in[1];
    const float* values_1 = (const float*)d_in[2];
    const void*  v1_mask  = d_in[3];
    const float* values_2 = (const float*)d_in[4];
    const void*  v2_mask  = d_in[5];
    const float* Wq       = (const float*)d_in[6];
    const float* Wk       = (const float*)d_in[7];
    const float* scaling  = (const float*)d_in[8];
    float* out = (float*)d_out;

    _Float16* pqw = (_Float16*)d_ws;                       // B*L*H   (4 MB)
    _Float16* pkw = pqw + (size_t)B * L * H;               // 4 MB
    _Float16* vt1 = pkw + (size_t)B * L * H;               // B*L*D   (8 MB)
    _Float16* vt2 = vt1 + (size_t)B * L * D;               // 8 MB
    float* fb1   = (float*)(vt2 + (size_t)B * L * D);      // 64 KB
    float* fb2   = fb1 + B * L;                            // 64 KB
    _Float16* Wf = (_Float16*)(fb2 + B * L);               // 128 KB

    prep_kernel<<<dim3(16, 2), 256, 0, stream>>>(
        v1_mask, v2_mask, Wq, Wk, fb1, fb2, Wf);
    proj_mfma_kernel<<<dim3(B * L / 64, 2, 2), 256, 0, stream>>>(
        queries, keys, Wf, scaling, pqw, pkw);
    vtrans_kernel<<<dim3(L / 64, D / 64, B * 2), 256, 0, stream>>>(
        values_1, values_2, vt1, vt2);
    attn_fused_kernel<<<dim3(L / 64, B, 2), 256, 0, stream>>>(
        pqw, pkw, fb1, fb2, vt1, vt2, out);
}